// Round 2
// baseline (693.868 us; speedup 1.0000x reference)
//
#include <hip/hip_runtime.h>

constexpr int DIM = 96;
constexpr int HW  = DIM * DIM;            // 9216
constexpr int DHW = DIM * DIM * DIM;      // 884736
constexpr int NC  = 64;
constexpr int NK  = 27;

constexpr int TZ = 4, TY = 8, TX = 32;    // block tile (z,y,x)

// No LDS, no barriers: each thread owns 4 x-voxels and reads its 6-float
// moving windows straight from global (L1/L2-resident: one block touches
// ~2KB of a moving channel; one full channel slice = 3.4MB < 4MiB XCD L2).
__global__ __launch_bounds__(256, 2)
void wincorr_kernel(const float* __restrict__ fixed_,
                    const float* __restrict__ moving,
                    float* __restrict__ out)
{
    const int tid = threadIdx.x;
    const int tx = tid & 7;          // 8 x-chunks of 4 floats
    const int ty = (tid >> 3) & 7;   // 8 y
    const int tz = tid >> 6;         // 4 z
    const int x0 = blockIdx.x * TX + 4 * tx;
    const int y  = blockIdx.y * TY + ty;
    const int z  = blockIdx.z * TZ + tz;

    // 9 clamped (z,y) row offsets — channel-invariant (edge padding).
    int rowoff[9];
#pragma unroll
    for (int dz = 0; dz < 3; ++dz) {
        const int zi = min(max(z + dz - 1, 0), DIM - 1);
#pragma unroll
        for (int dy = 0; dy < 3; ++dy) {
            const int yi = min(max(y + dy - 1, 0), DIM - 1);
            rowoff[dz * 3 + dy] = zi * HW + yi * DIM;
        }
    }
    // x-edge clamps: window covers m[x0-1 .. x0+4]
    const int xl = max(x0 - 1, 0);        // == clamp(x0-1)
    const int xr = min(x0 + 4, DIM - 1);  // == clamp(x0+4)
    const int foff = z * HW + y * DIM + x0;

    float acc[NK][4];
#pragma unroll
    for (int k = 0; k < NK; ++k)
#pragma unroll
        for (int j = 0; j < 4; ++j) acc[k][j] = 0.f;

    const float* mc = moving;
    const float* fc = fixed_ + foff;

    for (int c = 0; c < NC; ++c, mc += DHW, fc += DHW) {
        const float4 fv = *(const float4*)fc;   // aligned, in-range

#pragma unroll
        for (int r = 0; r < 9; ++r) {
            const float* row = mc + rowoff[r];
            // w[i] = m[clamp(x0-1+i)], i = 0..5
            const float  w0 = row[xl];                      // b32
            const float4 wm = *(const float4*)(row + x0);   // b128, 16B-aligned, x0<=92
            const float  w5 = row[xr];                      // b32
            const float w[6] = {w0, wm.x, wm.y, wm.z, wm.w, w5};
            const int kb = r * 3;   // k = (dz*3+dy)*3 + dx
#pragma unroll
            for (int dx = 0; dx < 3; ++dx) {
                acc[kb + dx][0] += fv.x * w[dx + 0];
                acc[kb + dx][1] += fv.y * w[dx + 1];
                acc[kb + dx][2] += fv.z * w[dx + 2];
                acc[kb + dx][3] += fv.w * w[dx + 3];
            }
        }
    }

    // scale = 64^-0.5 = 0.125 exactly
#pragma unroll
    for (int k = 0; k < NK; ++k) {
        float4 o;
        o.x = acc[k][0] * 0.125f;
        o.y = acc[k][1] * 0.125f;
        o.z = acc[k][2] * 0.125f;
        o.w = acc[k][3] * 0.125f;
        *(float4*)(out + k * DHW + foff) = o;
    }
}

extern "C" void kernel_launch(void* const* d_in, const int* in_sizes, int n_in,
                              void* d_out, int out_size, void* d_ws, size_t ws_size,
                              hipStream_t stream) {
    const float* fixed_  = (const float*)d_in[0];
    const float* moving  = (const float*)d_in[1];
    float* out = (float*)d_out;
    dim3 grid(DIM / TX, DIM / TY, DIM / TZ);   // 3 x 12 x 24 = 864 blocks
    dim3 block(256);
    wincorr_kernel<<<grid, block, 0, stream>>>(fixed_, moving, out);
}